// Round 2
// baseline (1242.816 us; speedup 1.0000x reference)
//
#include <hip/hip_runtime.h>
#include <math.h>

#define DIM 512
#define EPS 1e-8f

// ---------------------------------------------------------------------------
// Kernel A: normalize queries  qhat[b,:] = q[b,:] / max(||q[b,:]||, EPS)
// one block per b, 256 threads, 2 elements/thread
// ---------------------------------------------------------------------------
__global__ __launch_bounds__(256) void norm_q(const float* __restrict__ q,
                                              float* __restrict__ qhat) {
    __shared__ float red[4];
    const int b = blockIdx.x, tid = threadIdx.x;
    const float a0 = q[b * DIM + tid];
    const float a1 = q[b * DIM + 256 + tid];
    float s = a0 * a0 + a1 * a1;
    #pragma unroll
    for (int off = 32; off > 0; off >>= 1) s += __shfl_down(s, off);
    if ((tid & 63) == 0) red[tid >> 6] = s;
    __syncthreads();
    if (tid == 0) {
        float t = red[0] + red[1] + red[2] + red[3];
        red[0] = 1.f / fmaxf(sqrtf(t), EPS);
    }
    __syncthreads();
    const float inv = red[0];
    qhat[b * DIM + tid]       = a0 * inv;
    qhat[b * DIM + 256 + tid] = a1 * inv;
}

// ---------------------------------------------------------------------------
// Kernel B: memory-context inverse norms  mninv[m] = 1/max(||mc[m,:]||, EPS)
// one wave per row, 4 rows per block
// ---------------------------------------------------------------------------
__global__ __launch_bounds__(256) void norm_m(const float* __restrict__ mc,
                                              float* __restrict__ mninv, int M) {
    const int wid = threadIdx.x >> 6, lane = threadIdx.x & 63;
    const int m = blockIdx.x * 4 + wid;
    if (m >= M) return;
    const float4* r = (const float4*)(mc + (long)m * DIM);
    const float4 v0 = r[lane * 2];
    const float4 v1 = r[lane * 2 + 1];
    float s = v0.x * v0.x + v0.y * v0.y + v0.z * v0.z + v0.w * v0.w
            + v1.x * v1.x + v1.y * v1.y + v1.z * v1.z + v1.w * v1.w;
    #pragma unroll
    for (int off = 32; off > 0; off >>= 1) s += __shfl_down(s, off);
    if (lane == 0) mninv[m] = 1.f / fmaxf(sqrtf(s), EPS);
}

// ---------------------------------------------------------------------------
// Kernel C: cos[b,m] = qhat[b,:] . (mc[m,:] * mninv[m])
// grid (ceil(M/64), ceil(B/64)); 256 threads; 64m x 64b tile, acc 4x4/thread
// Tile is 64 rows x 32 cols = 2048 elems -> 8 staging iters of 256 threads.
// LDS stride 33 floats -> conflict-free reads.
// ---------------------------------------------------------------------------
#define KC 32
__global__ __launch_bounds__(256) void cos_gemm(const float* __restrict__ mc,
                                                const float* __restrict__ mninv,
                                                const float* __restrict__ qhat,
                                                float* __restrict__ cosm,
                                                int M, int B) {
    __shared__ float Tm[64 * 33];
    __shared__ float Tq[64 * 33];
    const int tid = threadIdx.x;
    const int tx = tid & 15;   // m lane (16)
    const int ty = tid >> 4;   // b group (16)
    const int mg0 = blockIdx.x * 64;
    const int b0  = blockIdx.y * 64;
    float acc[4][4] = {};
    for (int kc = 0; kc < DIM; kc += KC) {
        __syncthreads();
        #pragma unroll
        for (int t = 0; t < 8; ++t) {           // 8*256 = 2048 = 64x32 tile
            const int f = tid + t * 256;
            const int row = f >> 5, col = f & 31;
            const int m = mg0 + row;
            float v = 0.f;
            if (m < M) v = mc[(long)m * DIM + kc + col] * mninv[m];
            Tm[row * 33 + col] = v;
        }
        #pragma unroll
        for (int t = 0; t < 8; ++t) {
            const int f = tid + t * 256;
            const int row = f >> 5, col = f & 31;
            const int b = b0 + row;
            float v = 0.f;
            if (b < B) v = qhat[(long)b * DIM + kc + col];
            Tq[row * 33 + col] = v;
        }
        __syncthreads();
        #pragma unroll
        for (int kk = 0; kk < KC; ++kk) {
            float a[4], qv[4];
            #pragma unroll
            for (int i = 0; i < 4; ++i) a[i] = Tm[(tx + 16 * i) * 33 + kk];
            #pragma unroll
            for (int j = 0; j < 4; ++j) qv[j] = Tq[(ty * 4 + j) * 33 + kk];
            #pragma unroll
            for (int i = 0; i < 4; ++i)
                #pragma unroll
                for (int j = 0; j < 4; ++j)
                    acc[i][j] += a[i] * qv[j];
        }
    }
    #pragma unroll
    for (int j = 0; j < 4; ++j) {
        const int b = b0 + ty * 4 + j;
        if (b < B) {
            #pragma unroll
            for (int i = 0; i < 4; ++i) {
                const int m = mg0 + tx + 16 * i;
                if (m < M) cosm[(long)b * M + m] = acc[i][j];
            }
        }
    }
}

// ---------------------------------------------------------------------------
// Kernel D: per-row top-K (K<=64) + softmax weights.
// One block per b. Row copied to dynamic LDS; K iterations of block argmax
// with lowest-index tie-break (matches jax.lax.top_k), mask, repeat.
// ---------------------------------------------------------------------------
__global__ __launch_bounds__(256) void topk_softmax(const float* __restrict__ cosm,
                                                    float* __restrict__ wts,
                                                    int* __restrict__ topi,
                                                    int M,
                                                    const int* __restrict__ kp) {
    extern __shared__ float vals[];   // [M]
    __shared__ float rv[4];
    __shared__ int   ri[4];
    __shared__ float topv[64];
    __shared__ int   topidx[64];
    __shared__ float bsum;
    const int tid = threadIdx.x;
    const int b = blockIdx.x;
    const float* row = cosm + (long)b * M;
    for (int i = tid; i < M; i += 256) vals[i] = row[i];
    __syncthreads();
    int K = *kp;
    if (K > 64) K = 64;
    for (int s = 0; s < K; ++s) {
        float best = -3e38f;
        int bi = 0x7fffffff;
        for (int i = tid; i < M; i += 256) {
            const float v = vals[i];
            if (v > best) { best = v; bi = i; }   // strict > keeps lowest i
        }
        #pragma unroll
        for (int off = 32; off > 0; off >>= 1) {
            const float ov = __shfl_down(best, off);
            const int   oi = __shfl_down(bi, off);
            if (ov > best || (ov == best && oi < bi)) { best = ov; bi = oi; }
        }
        if ((tid & 63) == 0) { rv[tid >> 6] = best; ri[tid >> 6] = bi; }
        __syncthreads();
        if (tid == 0) {
            float bb = rv[0]; int bbi = ri[0];
            #pragma unroll
            for (int w = 1; w < 4; ++w)
                if (rv[w] > bb || (rv[w] == bb && ri[w] < bbi)) { bb = rv[w]; bbi = ri[w]; }
            topv[s] = bb; topidx[s] = bbi;
            vals[bbi] = -3e38f;
        }
        __syncthreads();
    }
    if (tid == 0) {
        const float vmax = topv[0];        // selection order => topv[0] is max
        float ssum = 0.f;
        for (int i = 0; i < K; ++i) ssum += expf(topv[i] - vmax);
        bsum = 1.f / ssum;
    }
    __syncthreads();
    if (tid < K) {
        wts[b * 64 + tid]  = expf(topv[tid] - topv[0]) * bsum;
        topi[b * 64 + tid] = topidx[tid];
    }
}

// ---------------------------------------------------------------------------
// Kernel E: out[b,l,:] = (sum_k w[b,k] * mf[idx[b,k]*64 + l, :]) * w
//                        + enc[b,l,:] * (1-w)
// grid (32, B); 256 threads = 2 l-rows x 128 float4 lanes
// ---------------------------------------------------------------------------
__global__ __launch_bounds__(256) void gather_blend(const float* __restrict__ mf,
                                                    const float* __restrict__ enc,
                                                    const float* __restrict__ wts,
                                                    const int* __restrict__ topi,
                                                    const float* __restrict__ wptr,
                                                    const int* __restrict__ kp,
                                                    float* __restrict__ out) {
    __shared__ float w_s[64];
    __shared__ int   i_s[64];
    const int tid = threadIdx.x;
    const int b = blockIdx.y;
    int K = *kp;
    if (K > 64) K = 64;
    if (tid < K) {
        w_s[tid] = wts[b * 64 + tid];
        i_s[tid] = topi[b * 64 + tid];
    }
    __syncthreads();
    const int l  = blockIdx.x * 2 + (tid >> 7);
    const int d4 = tid & 127;
    const float4* mf4 = (const float4*)mf;
    float4 acc = {0.f, 0.f, 0.f, 0.f};
    for (int k = 0; k < K; ++k) {
        const long row = (long)i_s[k] * 64 + l;
        const float4 v = mf4[row * 128 + d4];
        const float wk = w_s[k];
        acc.x += wk * v.x; acc.y += wk * v.y;
        acc.z += wk * v.z; acc.w += wk * v.w;
    }
    const float w = *wptr;
    const float ew = 1.f - w;
    const long o = ((long)b * 64 + l) * 128 + d4;
    const float4 e = ((const float4*)enc)[o];
    float4 r;
    r.x = acc.x * w + e.x * ew;
    r.y = acc.y * w + e.y * ew;
    r.z = acc.z * w + e.z * ew;
    r.w = acc.w * w + e.w * ew;
    ((float4*)out)[o] = r;
}

// ---------------------------------------------------------------------------
extern "C" void kernel_launch(void* const* d_in, const int* in_sizes, int n_in,
                              void* d_out, int out_size, void* d_ws, size_t ws_size,
                              hipStream_t stream) {
    const float* enc  = (const float*)d_in[0];   // [B, 64, 512]
    const float* cmc  = (const float*)d_in[1];   // [B, 512]
    const float* mc   = (const float*)d_in[2];   // [M, 512]
    const float* mf   = (const float*)d_in[3];   // [rows, 512]
    const float* wptr = (const float*)d_in[4];   // [1]
    const int*   kp   = (const int*)d_in[5];     // scalar k

    const int B = in_sizes[1] / DIM;             // 128
    const int M = in_sizes[2] / DIM;             // 6304

    // workspace layout (floats)
    float* ws    = (float*)d_ws;
    float* qhat  = ws;                                   // B*512
    float* mninv = qhat + (size_t)B * DIM;               // M (padded to 64)
    float* cosm  = mninv + (size_t)((M + 63) & ~63);     // B*M
    float* wts   = cosm + (size_t)B * M;                 // B*64
    int*   topi  = (int*)(wts + (size_t)B * 64);         // B*64

    norm_q<<<B, 256, 0, stream>>>(cmc, qhat);
    norm_m<<<(M + 3) / 4, 256, 0, stream>>>(mc, mninv, M);
    dim3 gc((M + 63) / 64, (B + 63) / 64);
    cos_gemm<<<gc, 256, 0, stream>>>(mc, mninv, qhat, cosm, M, B);
    topk_softmax<<<B, 256, (size_t)M * sizeof(float), stream>>>(cosm, wts, topi, M, kp);
    dim3 ge(32, B);
    gather_blend<<<ge, 256, 0, stream>>>(mf, enc, wts, topi, wptr, kp, (float*)d_out);
}